// Round 2
// baseline (373.995 us; speedup 1.0000x reference)
//
#include <hip/hip_runtime.h>
#include <hip/hip_fp16.h>

#define FP8_MAX 448.0f
#define M_ 32768
#define N_ 1024
#define K_ 1024
#define BM 128
#define BN 128
#define BK 64

typedef _Float16 f16x8 __attribute__((ext_vector_type(8)));
typedef _Float16 f16x4 __attribute__((ext_vector_type(4)));
typedef float f32x4 __attribute__((ext_vector_type(4)));

__device__ inline void gload_lds16(const void* g, void* l) {
    __builtin_amdgcn_global_load_lds(
        (const __attribute__((address_space(1))) void*)g,
        (__attribute__((address_space(3))) void*)l,
        16, 0, 0);
}

// ---------------- Kernel 1: fused x-amax + per-row weight quant ----------------
// blocks [0,1024): weight row quant. blocks [1024,3072): x amax slices.
__global__ __launch_bounds__(256) void prep_kernel(const float* __restrict__ x,
                                                   const float* __restrict__ w,
                                                   unsigned* __restrict__ amax_bits,
                                                   float* __restrict__ wscale,
                                                   _Float16* __restrict__ wq,
                                                   int n) {
    __shared__ float sm[4];
    if (blockIdx.x < 1024) {
        int row = blockIdx.x;
        const float4* wr4 = (const float4*)(w + (size_t)row * K_);
        float4 v = wr4[threadIdx.x];  // 256 threads x 4 = 1024
        float m = fmaxf(fmaxf(fabsf(v.x), fabsf(v.y)), fmaxf(fabsf(v.z), fabsf(v.w)));
        #pragma unroll
        for (int off = 32; off > 0; off >>= 1)
            m = fmaxf(m, __shfl_down(m, off, 64));
        if ((threadIdx.x & 63) == 0) sm[threadIdx.x >> 6] = m;
        __syncthreads();
        m = fmaxf(fmaxf(sm[0], sm[1]), fmaxf(sm[2], sm[3]));
        float scale = fmaxf(m / FP8_MAX, 1e-12f);
        if (threadIdx.x == 0) wscale[row] = scale;
        float inv = 1.0f / scale;
        f16x4 o;
        o[0] = (_Float16)rintf(fminf(fmaxf(v.x * inv, -FP8_MAX), FP8_MAX));
        o[1] = (_Float16)rintf(fminf(fmaxf(v.y * inv, -FP8_MAX), FP8_MAX));
        o[2] = (_Float16)rintf(fminf(fmaxf(v.z * inv, -FP8_MAX), FP8_MAX));
        o[3] = (_Float16)rintf(fminf(fmaxf(v.w * inv, -FP8_MAX), FP8_MAX));
        ((f16x4*)(wq + (size_t)row * K_))[threadIdx.x] = o;
    } else {
        float m = 0.0f;
        const float4* x4 = (const float4*)x;
        int n4 = n >> 2;
        int stride = 2048 * 256;
        for (int i = (blockIdx.x - 1024) * 256 + threadIdx.x; i < n4; i += stride) {
            float4 v = x4[i];
            m = fmaxf(m, fmaxf(fmaxf(fabsf(v.x), fabsf(v.y)),
                               fmaxf(fabsf(v.z), fabsf(v.w))));
        }
        #pragma unroll
        for (int off = 32; off > 0; off >>= 1)
            m = fmaxf(m, __shfl_down(m, off, 64));
        if ((threadIdx.x & 63) == 0) sm[threadIdx.x >> 6] = m;
        __syncthreads();
        if (threadIdx.x == 0) {
            float b = fmaxf(fmaxf(sm[0], sm[1]), fmaxf(sm[2], sm[3]));
            atomicMax(amax_bits, __float_as_uint(b));  // nonneg float bits are monotone
        }
    }
}

// ---------------- Kernel 2: quant x to fp16 ----------------
__global__ __launch_bounds__(256) void quant_x_kernel(const float* __restrict__ x,
                                                      const unsigned* __restrict__ amax_bits,
                                                      _Float16* __restrict__ xq,
                                                      int n) {
    float amax = __uint_as_float(*amax_bits);
    float scale = fmaxf(amax / FP8_MAX, 1e-12f);
    float inv = 1.0f / scale;
    const float4* x4 = (const float4*)x;
    f16x4* o4 = (f16x4*)xq;
    int n4 = n >> 2;
    int stride = gridDim.x * blockDim.x;
    for (int i = blockIdx.x * blockDim.x + threadIdx.x; i < n4; i += stride) {
        float4 v = x4[i];
        f16x4 o;
        o[0] = (_Float16)rintf(fminf(fmaxf(v.x * inv, -FP8_MAX), FP8_MAX));
        o[1] = (_Float16)rintf(fminf(fmaxf(v.y * inv, -FP8_MAX), FP8_MAX));
        o[2] = (_Float16)rintf(fminf(fmaxf(v.z * inv, -FP8_MAX), FP8_MAX));
        o[3] = (_Float16)rintf(fminf(fmaxf(v.w * inv, -FP8_MAX), FP8_MAX));
        o4[i] = o;
    }
}

// ---------------- Kernel 3: fp16 MFMA GEMM + dequant epilogue ----------------
// C[m,n] = sum_k xq[m,k]*wq[n,k]; out = C*(iscale*wscale[n]) + bias[n]
// LDS rows are 128 B (BK=64 fp16). XOR-swizzle: LDS row `rw` holds global
// 16B-chunk (pos ^ (rw&7)) at position pos — implemented by permuting the
// per-lane GLOBAL source address (global_load_lds dest must stay contiguous).
__global__ __launch_bounds__(256) void gemm_kernel(const _Float16* __restrict__ xq,
                                                   const _Float16* __restrict__ wq,
                                                   const unsigned* __restrict__ amax_bits,
                                                   const float* __restrict__ wscale,
                                                   const float* __restrict__ bias,
                                                   float* __restrict__ out) {
    __shared__ __align__(16) _Float16 sA[BM * BK];
    __shared__ __align__(16) _Float16 sB[BN * BK];

    const int tid  = threadIdx.x;
    const int wave = tid >> 6;
    const int lane = tid & 63;
    const int q = lane >> 4;   // 0..3
    const int r = lane & 15;   // 0..15
    const int r7 = r & 7;
    const int wm = (wave >> 1) * 64;
    const int wn = (wave & 1) * 64;

    // A-sharing blocks differ by multiples of 256 (≡0 mod 8) → same XCD → L2 reuse.
    const int m0 = (int)(blockIdx.x & 255) * BM;
    const int n0 = (int)(blockIdx.x >> 8) * BN;

    // staging: thread t loads 16B; round rr covers rows rr*32..rr*32+31
    const int trow = tid >> 3;                               // 0..31
    const int tcol = (((tid & 7) ^ (trow & 7)) * 8);         // swizzled source chunk

    const _Float16* Ag = xq + ((size_t)(m0 + trow)) * K_ + tcol;
    const _Float16* Bg = wq + ((size_t)(n0 + trow)) * K_ + tcol;
    char* lA = (char*)sA + wave * 1024;  // wave-uniform base; HW adds lane*16
    char* lB = (char*)sB + wave * 1024;

    f32x4 acc[4][4] = {};

    for (int kt = 0; kt < K_; kt += BK) {
        #pragma unroll
        for (int rr = 0; rr < 4; ++rr) {
            gload_lds16(Ag + kt + (size_t)(rr * 32) * K_, lA + rr * 4096);
            gload_lds16(Bg + kt + (size_t)(rr * 32) * K_, lB + rr * 4096);
        }
        __syncthreads();
        #pragma unroll
        for (int kk = 0; kk < BK; kk += 32) {
            f16x8 a[4], b[4];
            const int chunk = q + (kk >> 3);   // 16B-chunk index within the row
            const int pos = (chunk ^ r7) * 8;  // swizzled position (halves)
            #pragma unroll
            for (int i = 0; i < 4; ++i)
                a[i] = *(const f16x8*)&sA[(wm + i * 16 + r) * BK + pos];
            #pragma unroll
            for (int j = 0; j < 4; ++j)
                b[j] = *(const f16x8*)&sB[(wn + j * 16 + r) * BK + pos];
            #pragma unroll
            for (int i = 0; i < 4; ++i)
                #pragma unroll
                for (int j = 0; j < 4; ++j)
                    acc[i][j] = __builtin_amdgcn_mfma_f32_16x16x32_f16(a[i], b[j], acc[i][j], 0, 0, 0);
        }
        __syncthreads();
    }

    float amax = __uint_as_float(*amax_bits);
    float iscale = fmaxf(amax / FP8_MAX, 1e-12f);

    #pragma unroll
    for (int j = 0; j < 4; ++j) {
        int col = n0 + wn + j * 16 + r;
        float sc = iscale * wscale[col];
        float bs = bias[col];
        #pragma unroll
        for (int i = 0; i < 4; ++i) {
            int rowb = m0 + wm + i * 16 + q * 4;
            #pragma unroll
            for (int t = 0; t < 4; ++t)
                out[(size_t)(rowb + t) * N_ + col] = acc[i][j][t] * sc + bs;
        }
    }
}

extern "C" void kernel_launch(void* const* d_in, const int* in_sizes, int n_in,
                              void* d_out, int out_size, void* d_ws, size_t ws_size,
                              hipStream_t stream) {
    const float* x    = (const float*)d_in[0];
    const float* w    = (const float*)d_in[1];
    const float* bias = (const float*)d_in[2];
    float* out = (float*)d_out;

    char* ws = (char*)d_ws;
    unsigned* amax_bits = (unsigned*)ws;                       // 4 B
    float* wscale       = (float*)(ws + 256);                  // 4 KB
    _Float16* xq        = (_Float16*)(ws + 8192);              // 64 MB
    _Float16* wq        = (_Float16*)(ws + 8192 + (size_t)M_ * K_ * 2);  // 2 MB

    hipMemsetAsync(amax_bits, 0, 4, stream);
    prep_kernel<<<3072, 256, 0, stream>>>(x, w, amax_bits, wscale, wq, M_ * K_);
    quant_x_kernel<<<8192, 256, 0, stream>>>(x, amax_bits, xq, M_ * K_);
    gemm_kernel<<<2048, 256, 0, stream>>>(xq, wq, amax_bits, wscale, bias, out);
}

// Round 3
// 341.415 us; speedup vs baseline: 1.0954x; 1.0954x over previous
//
#include <hip/hip_runtime.h>
#include <hip/hip_fp16.h>

#define FP8_MAX 448.0f
#define M_ 32768
#define N_ 1024
#define K_ 1024
#define BM 128
#define BN 128
#define BK 64

typedef _Float16 f16x8 __attribute__((ext_vector_type(8)));
typedef _Float16 f16x4 __attribute__((ext_vector_type(4)));
typedef float f32x16 __attribute__((ext_vector_type(16)));

__device__ inline void gload_lds16(const void* g, void* l) {
    __builtin_amdgcn_global_load_lds(
        (const __attribute__((address_space(1))) void*)g,
        (__attribute__((address_space(3))) void*)l,
        16, 0, 0);
}

// ---------------- Kernel 1: weight quant + x partial amax (slot-based, no memset) ----
// blocks [0,1024): per-row weight quant. blocks [1024,3072): x amax partials.
__global__ __launch_bounds__(256) void prep_kernel(const float* __restrict__ x,
                                                   const float* __restrict__ w,
                                                   float* __restrict__ xamax_part,
                                                   float* __restrict__ wscale,
                                                   _Float16* __restrict__ wq,
                                                   int n) {
    __shared__ float sm[4];
    if (blockIdx.x < 1024) {
        int row = blockIdx.x;
        const float4* wr4 = (const float4*)(w + (size_t)row * K_);
        float4 v = wr4[threadIdx.x];  // 256 threads x 4 = 1024
        float m = fmaxf(fmaxf(fabsf(v.x), fabsf(v.y)), fmaxf(fabsf(v.z), fabsf(v.w)));
        #pragma unroll
        for (int off = 32; off > 0; off >>= 1)
            m = fmaxf(m, __shfl_down(m, off, 64));
        if ((threadIdx.x & 63) == 0) sm[threadIdx.x >> 6] = m;
        __syncthreads();
        m = fmaxf(fmaxf(sm[0], sm[1]), fmaxf(sm[2], sm[3]));
        float scale = fmaxf(m / FP8_MAX, 1e-12f);
        if (threadIdx.x == 0) wscale[row] = scale;
        float inv = 1.0f / scale;
        f16x4 o;
        o[0] = (_Float16)rintf(fminf(fmaxf(v.x * inv, -FP8_MAX), FP8_MAX));
        o[1] = (_Float16)rintf(fminf(fmaxf(v.y * inv, -FP8_MAX), FP8_MAX));
        o[2] = (_Float16)rintf(fminf(fmaxf(v.z * inv, -FP8_MAX), FP8_MAX));
        o[3] = (_Float16)rintf(fminf(fmaxf(v.w * inv, -FP8_MAX), FP8_MAX));
        ((f16x4*)(wq + (size_t)row * K_))[threadIdx.x] = o;
    } else {
        float m = 0.0f;
        const float4* x4 = (const float4*)x;
        int n4 = n >> 2;
        int stride = 2048 * 256;
        for (int i = (blockIdx.x - 1024) * 256 + threadIdx.x; i < n4; i += stride) {
            float4 v = x4[i];
            m = fmaxf(m, fmaxf(fmaxf(fabsf(v.x), fabsf(v.y)),
                               fmaxf(fabsf(v.z), fabsf(v.w))));
        }
        #pragma unroll
        for (int off = 32; off > 0; off >>= 1)
            m = fmaxf(m, __shfl_down(m, off, 64));
        if ((threadIdx.x & 63) == 0) sm[threadIdx.x >> 6] = m;
        __syncthreads();
        if (threadIdx.x == 0) {
            xamax_part[blockIdx.x - 1024] =
                fmaxf(fmaxf(sm[0], sm[1]), fmaxf(sm[2], sm[3]));
        }
    }
}

// ---------------- Kernel 2: reduce partials + quant x to fp16 ----------------
__global__ __launch_bounds__(256) void quant_x_kernel(const float* __restrict__ x,
                                                      const float* __restrict__ xamax_part,
                                                      float* __restrict__ xscale_out,
                                                      _Float16* __restrict__ xq,
                                                      int n) {
    // every block reduces the 2048 partials (L2-hot, deterministic)
    __shared__ float sm[4];
    const float4* p4 = (const float4*)xamax_part;  // 512 float4
    float4 a = p4[threadIdx.x];
    float4 b = p4[threadIdx.x + 256];
    float m = fmaxf(fmaxf(fmaxf(a.x, a.y), fmaxf(a.z, a.w)),
                    fmaxf(fmaxf(b.x, b.y), fmaxf(b.z, b.w)));
    #pragma unroll
    for (int off = 32; off > 0; off >>= 1)
        m = fmaxf(m, __shfl_down(m, off, 64));
    if ((threadIdx.x & 63) == 0) sm[threadIdx.x >> 6] = m;
    __syncthreads();
    float amax = fmaxf(fmaxf(sm[0], sm[1]), fmaxf(sm[2], sm[3]));
    float scale = fmaxf(amax / FP8_MAX, 1e-12f);
    if (threadIdx.x == 0) xscale_out[0] = scale;  // all blocks write same value
    float inv = 1.0f / scale;

    const float4* x4 = (const float4*)x;
    f16x4* o4 = (f16x4*)xq;
    int n4 = n >> 2;
    int stride = gridDim.x * blockDim.x;
    for (int i = blockIdx.x * blockDim.x + threadIdx.x; i < n4; i += stride) {
        float4 v = x4[i];
        f16x4 o;
        o[0] = (_Float16)rintf(fminf(fmaxf(v.x * inv, -FP8_MAX), FP8_MAX));
        o[1] = (_Float16)rintf(fminf(fmaxf(v.y * inv, -FP8_MAX), FP8_MAX));
        o[2] = (_Float16)rintf(fminf(fmaxf(v.z * inv, -FP8_MAX), FP8_MAX));
        o[3] = (_Float16)rintf(fminf(fmaxf(v.w * inv, -FP8_MAX), FP8_MAX));
        o4[i] = o;
    }
}

// ---------------- Kernel 3: fp16 MFMA GEMM (32x32x16) + dequant epilogue ----------
// C[m,n] = sum_k xq[m,k]*wq[n,k]; out = C*(iscale*wscale[n]) + bias[n]
// LDS rows 128 B; XOR swizzle: physical slot s of row rw holds logical chunk
// s^(rw&7) (permuted on the GLOBAL source side to satisfy global_load_lds's
// contiguous-dest constraint). Readback: logical chunk c -> slot c^(rw&7).
__global__ __launch_bounds__(256) void gemm_kernel(const _Float16* __restrict__ xq,
                                                   const _Float16* __restrict__ wq,
                                                   const float* __restrict__ xscale,
                                                   const float* __restrict__ wscale,
                                                   const float* __restrict__ bias,
                                                   float* __restrict__ out) {
    __shared__ __align__(16) _Float16 sA[BM * BK];
    __shared__ __align__(16) _Float16 sB[BN * BK];

    const int tid  = threadIdx.x;
    const int wave = tid >> 6;
    const int lane = tid & 63;
    const int h   = lane >> 5;    // half-wave
    const int m32 = lane & 31;
    const int m7  = m32 & 7;
    const int wm = (wave >> 1) * 64;
    const int wn = (wave & 1) * 64;

    // A-sharing blocks differ by multiples of 256 (≡0 mod 8) → same XCD → L2 reuse.
    const int m0 = (int)(blockIdx.x & 255) * BM;
    const int n0 = (int)(blockIdx.x >> 8) * BN;

    // staging: thread t loads 16B; round rr covers rows rr*32..rr*32+31
    const int trow = tid >> 3;                               // 0..31
    const int tcol = (((tid & 7) ^ (trow & 7)) * 8);         // swizzled source chunk

    const _Float16* Ag = xq + ((size_t)(m0 + trow)) * K_ + tcol;
    const _Float16* Bg = wq + ((size_t)(n0 + trow)) * K_ + tcol;
    char* lA = (char*)sA + wave * 1024;  // wave-uniform base; HW adds lane*16
    char* lB = (char*)sB + wave * 1024;

    f32x16 acc[2][2] = {};

    for (int kt = 0; kt < K_; kt += BK) {
        #pragma unroll
        for (int rr = 0; rr < 4; ++rr) {
            gload_lds16(Ag + kt + (size_t)(rr * 32) * K_, lA + rr * 4096);
            gload_lds16(Bg + kt + (size_t)(rr * 32) * K_, lB + rr * 4096);
        }
        __syncthreads();
        #pragma unroll
        for (int ks = 0; ks < 4; ++ks) {       // K chunks of 16 within the tile
            f16x8 a[2], b[2];
            const int chunk = ks * 2 + h;      // logical 16B-chunk (8 halves)
            const int pos = (chunk ^ m7) * 8;  // swizzled physical offset (halves)
            #pragma unroll
            for (int i = 0; i < 2; ++i)
                a[i] = *(const f16x8*)&sA[(wm + i * 32 + m32) * BK + pos];
            #pragma unroll
            for (int j = 0; j < 2; ++j)
                b[j] = *(const f16x8*)&sB[(wn + j * 32 + m32) * BK + pos];
            #pragma unroll
            for (int i = 0; i < 2; ++i)
                #pragma unroll
                for (int j = 0; j < 2; ++j)
                    acc[i][j] = __builtin_amdgcn_mfma_f32_32x32x16_f16(a[i], b[j], acc[i][j], 0, 0, 0);
        }
        __syncthreads();
    }

    float iscale = xscale[0];

    #pragma unroll
    for (int j = 0; j < 2; ++j) {
        int col = n0 + wn + j * 32 + m32;
        float sc = iscale * wscale[col];
        float bs = bias[col];
        #pragma unroll
        for (int i = 0; i < 2; ++i) {
            int rb = m0 + wm + i * 32 + 4 * h;
            #pragma unroll
            for (int reg = 0; reg < 16; ++reg) {
                int row = rb + (reg & 3) + 8 * (reg >> 2);
                out[(size_t)row * N_ + col] = acc[i][j][reg] * sc + bs;
            }
        }
    }
}

extern "C" void kernel_launch(void* const* d_in, const int* in_sizes, int n_in,
                              void* d_out, int out_size, void* d_ws, size_t ws_size,
                              hipStream_t stream) {
    const float* x    = (const float*)d_in[0];
    const float* w    = (const float*)d_in[1];
    const float* bias = (const float*)d_in[2];
    float* out = (float*)d_out;

    char* ws = (char*)d_ws;
    float* xscale      = (float*)ws;                           // 4 B
    float* xamax_part  = (float*)(ws + 1024);                  // 8 KB (2048 slots)
    float* wscale      = (float*)(ws + 16384);                 // 4 KB
    _Float16* wq       = (_Float16*)(ws + 32768);              // 2 MB
    _Float16* xq       = (_Float16*)(ws + (4u << 20));         // 64 MB

    prep_kernel<<<3072, 256, 0, stream>>>(x, w, xamax_part, wscale, wq, M_ * K_);
    quant_x_kernel<<<8192, 256, 0, stream>>>(x, xamax_part, xscale, xq, M_ * K_);
    gemm_kernel<<<2048, 256, 0, stream>>>(xq, wq, xscale, wscale, bias, out);
}